// Round 1
// baseline (534.705 us; speedup 1.0000x reference)
//
#include <hip/hip_runtime.h>

#define NPOLY 256
#define VPP   64
#define LCH   32
#define NV    (1 + NPOLY * VPP)   // 16385 vectors per batch in `data`
#define LN_EPS 1e-5f

// ---------------------------------------------------------------------------
// Kernel A: fused 3-layer MLP per polyline. One wave (64 threads) per poly,
// thread t owns row t. Produces Ph[b,p,0:128] = m2 (P = [m2, m2]).
// ---------------------------------------------------------------------------
__global__ __launch_bounds__(64, 2) void vn_mlp(
    const float* __restrict__ data,
    const float* __restrict__ W0, const float* __restrict__ b0,
    const float* __restrict__ g0, const float* __restrict__ be0,
    const float* __restrict__ W1, const float* __restrict__ b1,
    const float* __restrict__ g1, const float* __restrict__ be1,
    const float* __restrict__ W2, const float* __restrict__ b2,
    const float* __restrict__ g2, const float* __restrict__ be2,
    float* __restrict__ Ph)
{
    // Private per-row LDS scratch (dynamic-j indexed values live here, not in
    // dynamically-indexed registers). Pitch 65: bank = (t + j) % 32 -> 2-way
    // aliasing only (free on CDNA4).
    __shared__ float buf[64 * 65];
    __shared__ float au1s[64];
    __shared__ float au2s[128];
    __shared__ float m2s[128];

    const int blk = blockIdx.x;          // b * NPOLY + p
    const int t   = threadIdx.x;         // row within poly, 0..63
    const int bb  = blk >> 8;
    const int pp  = blk & 255;

    float* myrow = buf + t * 65;

    // ---- stage input row (32 ch), zero last channel ----
    const float4* row4 =
        (const float4*)(data + ((size_t)bb * NV + 1 + (size_t)pp * VPP + t) * LCH);
    #pragma unroll
    for (int i = 0; i < 8; i++) {
        float4 v = row4[i];
        if (i == 7) v.w = 0.f;           // vecs[:, :, -1] = 0
        myrow[4 * i + 0] = v.x;
        myrow[4 * i + 1] = v.y;
        myrow[4 * i + 2] = v.z;
        myrow[4 * i + 3] = v.w;
    }
    __syncthreads();

    // ================= layer 0: 32 -> 32 =================
    float h0[32];
    #pragma unroll
    for (int o = 0; o < 32; o++) h0[o] = b0[o];
    for (int j = 0; j < 32; j++) {
        float xv = myrow[j];
        #pragma unroll
        for (int o = 0; o < 32; o++) h0[o] = fmaf(xv, W0[j * 32 + o], h0[o]);
    }
    float sum = 0.f, sq = 0.f;
    #pragma unroll
    for (int o = 0; o < 32; o++) { sum += h0[o]; sq += h0[o] * h0[o]; }
    float mu   = sum * (1.f / 32.f);
    float var  = sq * (1.f / 32.f) - mu * mu;
    float rinv = rsqrtf(var + LN_EPS);
    #pragma unroll
    for (int o = 0; o < 32; o++)
        h0[o] = fmaxf(fmaf(g0[o] * rinv, h0[o] - mu, be0[o]), 0.f);

    // agg0 = column max over the 64 rows (cross-lane butterfly)
    float a0[32];
    #pragma unroll
    for (int o = 0; o < 32; o++) {
        float v = h0[o];
        #pragma unroll
        for (int s = 1; s < 64; s <<= 1) v = fmaxf(v, __shfl_xor(v, s, 64));
        a0[o] = v;
    }
    // uniform contribution of agg0 through W1's bottom half; lane t computes
    // output channel t.  Includes b1.
    float au1 = b1[t];
    #pragma unroll
    for (int j = 0; j < 32; j++)
        au1 = fmaf(a0[j], W1[(32 + j) * 64 + t], au1);
    au1s[t] = au1;
    // store h0 row back to LDS (x is dead)
    #pragma unroll
    for (int o = 0; o < 32; o++) myrow[o] = h0[o];
    __syncthreads();

    // ================= layer 1: 64 -> 64 (per-row part: 32 in) =============
    float h1[64];
    #pragma unroll
    for (int o = 0; o < 64; o++) h1[o] = au1s[o];
    for (int j = 0; j < 32; j++) {
        float hv = myrow[j];
        #pragma unroll
        for (int o = 0; o < 64; o++) h1[o] = fmaf(hv, W1[j * 64 + o], h1[o]);
    }
    sum = 0.f; sq = 0.f;
    #pragma unroll
    for (int o = 0; o < 64; o++) { sum += h1[o]; sq += h1[o] * h1[o]; }
    mu   = sum * (1.f / 64.f);
    var  = sq * (1.f / 64.f) - mu * mu;
    rinv = rsqrtf(var + LN_EPS);
    #pragma unroll
    for (int o = 0; o < 64; o++)
        h1[o] = fmaxf(fmaf(g1[o] * rinv, h1[o] - mu, be1[o]), 0.f);

    float a1[64];
    #pragma unroll
    for (int o = 0; o < 64; o++) {
        float v = h1[o];
        #pragma unroll
        for (int s = 1; s < 64; s <<= 1) v = fmaxf(v, __shfl_xor(v, s, 64));
        a1[o] = v;
    }
    // agg1 through W2's bottom half; lane t computes channels t and 64+t.
    float au2a = b2[t], au2b = b2[64 + t];
    #pragma unroll
    for (int j = 0; j < 64; j++) {
        au2a = fmaf(a1[j], W2[(64 + j) * 128 + t], au2a);
        au2b = fmaf(a1[j], W2[(64 + j) * 128 + 64 + t], au2b);
    }
    au2s[t]      = au2a;
    au2s[64 + t] = au2b;
    #pragma unroll
    for (int o = 0; o < 64; o++) myrow[o] = h1[o];
    __syncthreads();

    // ================= layer 2: 128 -> 128 (per-row part: 64 in) ===========
    float a2[128];
    #pragma unroll
    for (int o = 0; o < 128; o++) a2[o] = au2s[o];
    for (int j = 0; j < 64; j++) {
        float hv = myrow[j];
        #pragma unroll
        for (int o = 0; o < 128; o++) a2[o] = fmaf(hv, W2[j * 128 + o], a2[o]);
    }
    sum = 0.f; sq = 0.f;
    #pragma unroll
    for (int o = 0; o < 128; o++) { sum += a2[o]; sq += a2[o] * a2[o]; }
    mu   = sum * (1.f / 128.f);
    var  = sq * (1.f / 128.f) - mu * mu;
    rinv = rsqrtf(var + LN_EPS);
    // LN + relu + cross-row max -> m2 (P = [m2, m2], store only m2)
    #pragma unroll
    for (int o = 0; o < 128; o++) {
        float v = fmaxf(fmaf(g2[o] * rinv, a2[o] - mu, be2[o]), 0.f);
        #pragma unroll
        for (int s = 1; s < 64; s <<= 1) v = fmaxf(v, __shfl_xor(v, s, 64));
        if (t == 0) m2s[o] = v;
    }
    __syncthreads();
    float* op = Ph + (size_t)blk * 128;
    op[t]      = m2s[t];
    op[64 + t] = m2s[64 + t];
}

// ---------------------------------------------------------------------------
// Kernel B: attention tail. One block (256 threads = 4 waves) per batch.
//   q = P[b,agent] @ Wq + bq
//   scores[p] = P[b,p] . (Wk^T q) / 16      (q.bk shift cancels in softmax)
//   out = (sum_p att[p] P[b,p]) @ Wv + bv
// Ph holds only the 128 unique channels; full channel c maps to c & 127.
// ---------------------------------------------------------------------------
__global__ __launch_bounds__(256) void vn_attn(
    const float* __restrict__ data, const float* __restrict__ Ph,
    const float* __restrict__ Wq, const float* __restrict__ bq,
    const float* __restrict__ Wk, const float* __restrict__ bk,
    const float* __restrict__ Wv, const float* __restrict__ bv,
    float* __restrict__ out)
{
    __shared__ float Pa[256];
    __shared__ float qs[256];
    __shared__ float ts[256];
    __shared__ float tts[128];
    __shared__ float sc[256];
    __shared__ float pb[128];
    __shared__ float red[8];

    const int b    = blockIdx.x;
    const int tid  = threadIdx.x;
    const int lane = tid & 63;
    const int wave = tid >> 6;

    const float* PhB = Ph + (size_t)b * NPOLY * 128;
    const int agent  = (int)data[(size_t)b * NV * LCH];   // data[b,0,0]

    // agent row of P (256 channels, folded)
    Pa[tid] = PhB[(size_t)agent * 128 + (tid & 127)];
    __syncthreads();

    // q[c]
    float acc = bq[tid];
    for (int j = 0; j < 256; j++) acc = fmaf(Pa[j], Wq[j * 256 + tid], acc);
    qs[tid] = acc;
    __syncthreads();

    // t[j] = sum_c Wk[j,c] q[c]  (wave-cooperative per j, coalesced)
    for (int jj = 0; jj < 64; jj++) {
        const int j = wave * 64 + jj;
        const float* wkr = Wk + (size_t)j * 256;
        float p = wkr[lane] * qs[lane];
        p = fmaf(wkr[ 64 + lane], qs[ 64 + lane], p);
        p = fmaf(wkr[128 + lane], qs[128 + lane], p);
        p = fmaf(wkr[192 + lane], qs[192 + lane], p);
        #pragma unroll
        for (int s = 1; s < 64; s <<= 1) p += __shfl_xor(p, s, 64);
        if (lane == 0) ts[j] = p;
    }
    __syncthreads();
    if (tid < 128) tts[tid] = ts[tid] + ts[128 + tid];
    __syncthreads();

    // scores[p] = P[b,p] . t / 16  (wave-cooperative per p)
    for (int pi = 0; pi < 64; pi++) {
        const int p = wave * 64 + pi;
        const float* pr = PhB + (size_t)p * 128;
        float s = pr[lane] * tts[lane];
        s = fmaf(pr[64 + lane], tts[64 + lane], s);
        #pragma unroll
        for (int st = 1; st < 64; st <<= 1) s += __shfl_xor(s, st, 64);
        if (lane == 0) sc[p] = s * 0.0625f;
    }
    __syncthreads();

    // softmax over the 256 scores
    float sv = sc[tid];
    float mx = sv;
    #pragma unroll
    for (int s = 1; s < 64; s <<= 1) mx = fmaxf(mx, __shfl_xor(mx, s, 64));
    if (lane == 0) red[wave] = mx;
    __syncthreads();
    mx = fmaxf(fmaxf(red[0], red[1]), fmaxf(red[2], red[3]));
    float e  = expf(sv - mx);
    float sm = e;
    #pragma unroll
    for (int s = 1; s < 64; s <<= 1) sm += __shfl_xor(sm, s, 64);
    if (lane == 0) red[4 + wave] = sm;
    __syncthreads();
    const float tot = red[4] + red[5] + red[6] + red[7];
    sc[tid] = e / tot;
    __syncthreads();

    // pbar[c] = sum_p att[p] * P[b,p,c]  (unique 128 channels)
    if (tid < 128) {
        float a = 0.f;
        for (int p = 0; p < 256; p++)
            a = fmaf(sc[p], PhB[(size_t)p * 128 + tid], a);
        pb[tid] = a;
    }
    __syncthreads();

    // out[c] = bv[c] + sum_j pbar[j] Wv[j,c]
    float o = bv[tid];
    for (int j = 0; j < 256; j++)
        o = fmaf(pb[j & 127], Wv[j * 256 + tid], o);
    out[(size_t)b * 256 + tid] = o;
}

extern "C" void kernel_launch(void* const* d_in, const int* in_sizes, int n_in,
                              void* d_out, int out_size, void* d_ws, size_t ws_size,
                              hipStream_t stream)
{
    const float* data = (const float*)d_in[0];
    const float* W0 = (const float*)d_in[1];
    const float* b0 = (const float*)d_in[2];
    const float* g0 = (const float*)d_in[3];
    const float* be0= (const float*)d_in[4];
    const float* W1 = (const float*)d_in[5];
    const float* b1 = (const float*)d_in[6];
    const float* g1 = (const float*)d_in[7];
    const float* be1= (const float*)d_in[8];
    const float* W2 = (const float*)d_in[9];
    const float* b2 = (const float*)d_in[10];
    const float* g2 = (const float*)d_in[11];
    const float* be2= (const float*)d_in[12];
    const float* Wq = (const float*)d_in[13];
    const float* bq = (const float*)d_in[14];
    const float* Wk = (const float*)d_in[15];
    const float* bk = (const float*)d_in[16];
    const float* Wv = (const float*)d_in[17];
    const float* bv = (const float*)d_in[18];

    float* Ph = (float*)d_ws;   // 32*256*128 floats = 4 MB (P = [m2, m2])

    vn_mlp<<<32 * NPOLY, 64, 0, stream>>>(data, W0, b0, g0, be0,
                                          W1, b1, g1, be1,
                                          W2, b2, g2, be2, Ph);
    vn_attn<<<32, 256, 0, stream>>>(data, Ph, Wq, bq, Wk, bk, Wv, bv,
                                    (float*)d_out);
}

// Round 2
// 233.475 us; speedup vs baseline: 2.2902x; 2.2902x over previous
//
#include <hip/hip_runtime.h>

#define NPOLY 256
#define VPP   64
#define LCH   32
#define NV    (1 + NPOLY * VPP)
#define LN_EPS 1e-5f

typedef __bf16 bf16x8 __attribute__((ext_vector_type(8)));
typedef float  f32x4  __attribute__((ext_vector_type(4)));

union U4B8 { uint4 u; bf16x8 v; };

__device__ __forceinline__ unsigned f2bf_u(float f) {
    unsigned u = __float_as_uint(f);
    return (u + 0x7FFFu + ((u >> 16) & 1u)) >> 16;   // RNE fp32 -> bf16 bits
}
__device__ __forceinline__ unsigned packbf(float a, float b) {
    return f2bf_u(a) | (f2bf_u(b) << 16);
}

// ---------------------------------------------------------------------------
// prep1: (a) fold Wq/Wk/Wv over the duplicated 128-channel halves of P,
//        (b) pack W0 / W1-top / W2-top into bf16 B-fragment order:
//        frag f, lane L: 8 bf16 = W[k0 + j][ct*16 + (L&15)], k0 = (L>>4)*8 (+ks*32)
//        stored as 64 x uint4 per fragment (1 KB) -> one coalesced b128/lane.
// ---------------------------------------------------------------------------
__global__ void vn_prep1(const float* __restrict__ W0, const float* __restrict__ W1,
                         const float* __restrict__ W2,
                         const float* __restrict__ Wq, const float* __restrict__ Wk,
                         const float* __restrict__ Wv,
                         float* __restrict__ Wqf, float* __restrict__ Wkf,
                         float* __restrict__ Wvf, uint4* __restrict__ wpack)
{
    int t = blockIdx.x * 256 + threadIdx.x;
    if (t < 3 * 32768) {
        int which = t >> 15, r = t & 32767;    // r = i*256+c, i<128
        const float* src = which == 0 ? Wq : which == 1 ? Wk : Wv;
        float*       dst = which == 0 ? Wqf : which == 1 ? Wkf : Wvf;
        dst[r] = src[r] + src[r + 128 * 256];
        return;
    }
    t -= 3 * 32768;
    if (t >= 22 * 64) return;
    int f = t >> 6, L = t & 63, q = L >> 4, m = L & 15;
    const float* src; int N, k0, col;
    if (f < 2)      { src = W0; N = 32;  k0 = q * 8;                 col = f * 16 + m; }
    else if (f < 6) { src = W1; N = 64;  k0 = q * 8;                 col = (f - 2) * 16 + m; }
    else { int g = f - 6; src = W2; N = 128; k0 = (g >> 3) * 32 + q * 8; col = (g & 7) * 16 + m; }
    float e[8];
    #pragma unroll
    for (int j = 0; j < 8; j++) e[j] = src[(k0 + j) * N + col];
    uint4 o;
    o.x = packbf(e[0], e[1]); o.y = packbf(e[2], e[3]);
    o.z = packbf(e[4], e[5]); o.w = packbf(e[6], e[7]);
    wpack[f * 64 + L] = o;
}

// ---------------------------------------------------------------------------
// prep2: Mff[i][j] = sum_c Wqf[i][c] * Wkf[j][c]   (128x128, K=256)
//        u0f[j]    = sum_c bq[c]    * Wkf[j][c]
// ---------------------------------------------------------------------------
__global__ void vn_prep2(const float* __restrict__ Wqf, const float* __restrict__ Wkf,
                         const float* __restrict__ bq,
                         float* __restrict__ Mff, float* __restrict__ u0f)
{
    int t = blockIdx.x * 256 + threadIdx.x;
    if (t < 16384) {
        int i = t >> 7, j = t & 127;
        const float* a = Wqf + i * 256;
        const float* b = Wkf + j * 256;
        float s = 0.f;
        for (int c = 0; c < 256; c++) s = fmaf(a[c], b[c], s);
        Mff[i * 128 + j] = s;
    } else if (t < 16512) {
        int j = t - 16384;
        const float* b = Wkf + j * 256;
        float s = 0.f;
        for (int c = 0; c < 256; c++) s = fmaf(bq[c], b[c], s);
        u0f[j] = s;
    }
}

// ---------------------------------------------------------------------------
// vn_mlp: one wave per poly, MFMA 16x16x32 bf16 for the three matmuls.
// C/D layout (m89-verified): col = lane&15, row = (lane>>4)*4 + reg.
// A layout (m120): A[m = lane&15][k = (lane>>4)*8 + j].
// h round-trips through LDS (row-major, pitch 72 bf16) for C->A transform.
// Uniform concat halves: agg @ W_bottom computed once per poly per lane.
// ---------------------------------------------------------------------------
__global__ __launch_bounds__(64, 2) void vn_mlp(
    const float* __restrict__ data, const uint4* __restrict__ wpack,
    const float* __restrict__ b0, const float* __restrict__ g0, const float* __restrict__ be0,
    const float* __restrict__ W1, const float* __restrict__ b1,
    const float* __restrict__ g1, const float* __restrict__ be1,
    const float* __restrict__ W2, const float* __restrict__ b2,
    const float* __restrict__ g2, const float* __restrict__ be2,
    float* __restrict__ Ph)
{
    __shared__ __align__(16) unsigned short hbuf[64 * 72];  // 9216 B
    __shared__ float fbuf[192];   // [0,64): agg bcast, [64,192): au bcast

    const int blk = blockIdx.x;
    const int L = threadIdx.x, q = L >> 4, m = L & 15;
    const int bb = blk >> 8, pp = blk & 255;

    // ---------------- layer 0 : 32 -> 32 ----------------
    const float* rowbase = data + ((size_t)bb * NV + 1 + (size_t)pp * VPP) * LCH;
    bf16x8 A0[4];
    #pragma unroll
    for (int rt = 0; rt < 4; rt++) {
        const float* rp = rowbase + (size_t)(rt * 16 + m) * LCH + q * 8;
        float4 u = *(const float4*)rp;
        float4 v = *(const float4*)(rp + 4);
        if (q == 3) v.w = 0.f;                 // vecs[:, :, -1] = 0
        U4B8 c;
        c.u.x = packbf(u.x, u.y); c.u.y = packbf(u.z, u.w);
        c.u.z = packbf(v.x, v.y); c.u.w = packbf(v.z, v.w);
        A0[rt] = c.v;
    }
    U4B8 t0, t1; t0.u = wpack[0 * 64 + L]; t1.u = wpack[1 * 64 + L];
    float bc0[2] = { b0[m], b0[16 + m] };
    f32x4 acc0[4][2];
    #pragma unroll
    for (int rt = 0; rt < 4; rt++) {
        {
            f32x4 a = { bc0[0], bc0[0], bc0[0], bc0[0] };
            acc0[rt][0] = __builtin_amdgcn_mfma_f32_16x16x32_bf16(A0[rt], t0.v, a, 0, 0, 0);
        }
        {
            f32x4 a = { bc0[1], bc0[1], bc0[1], bc0[1] };
            acc0[rt][1] = __builtin_amdgcn_mfma_f32_16x16x32_bf16(A0[rt], t1.v, a, 0, 0, 0);
        }
    }
    // LN (per row, N=32) + relu + col-max
    float g0c[2]  = { g0[m],  g0[16 + m]  };
    float be0c[2] = { be0[m], be0[16 + m] };
    float a0mx[2] = { 0.f, 0.f };
    #pragma unroll
    for (int rt = 0; rt < 4; rt++) {
        #pragma unroll
        for (int reg = 0; reg < 4; reg++) {
            float x0 = acc0[rt][0][reg], x1 = acc0[rt][1][reg];
            float rs = x0 + x1, rq = x0 * x0 + x1 * x1;
            #pragma unroll
            for (int s = 1; s < 16; s <<= 1) { rs += __shfl_xor(rs, s, 64); rq += __shfl_xor(rq, s, 64); }
            float mu = rs * (1.f / 32.f);
            float var = rq * (1.f / 32.f) - mu * mu;
            float ri = rsqrtf(var + LN_EPS);
            #pragma unroll
            for (int ct = 0; ct < 2; ct++) {
                float v = fmaxf(fmaf(g0c[ct] * ri, acc0[rt][ct][reg] - mu, be0c[ct]), 0.f);
                acc0[rt][ct][reg] = v;
                a0mx[ct] = fmaxf(a0mx[ct], v);
            }
        }
    }
    #pragma unroll
    for (int ct = 0; ct < 2; ct++) {
        float v = a0mx[ct];
        v = fmaxf(v, __shfl_xor(v, 16, 64));
        v = fmaxf(v, __shfl_xor(v, 32, 64));
        a0mx[ct] = v;
    }
    if (q == 0) { fbuf[m] = a0mx[0]; fbuf[16 + m] = a0mx[1]; }
    __syncthreads();
    // uniform part: au1[n=L] = b1[L] + sum_j agg0[j] * W1[32+j][L]
    float au1 = b1[L];
    for (int j = 0; j < 32; j++)
        au1 = fmaf(fbuf[j], W1[(32 + j) * 64 + L], au1);
    // stage h0 (bf16) for next layer's A-fragments
    #pragma unroll
    for (int rt = 0; rt < 4; rt++)
        #pragma unroll
        for (int reg = 0; reg < 4; reg++) {
            int row = rt * 16 + q * 4 + reg;
            hbuf[row * 72 + m]      = (unsigned short)f2bf_u(acc0[rt][0][reg]);
            hbuf[row * 72 + 16 + m] = (unsigned short)f2bf_u(acc0[rt][1][reg]);
        }
    __syncthreads();
    fbuf[64 + L] = au1;
    __syncthreads();

    // ---------------- layer 1 : 64(per-row 32) -> 64 ----------------
    bf16x8 A1[4];
    #pragma unroll
    for (int rt = 0; rt < 4; rt++) {
        U4B8 c; c.u = *(const uint4*)(hbuf + (rt * 16 + m) * 72 + q * 8);
        A1[rt] = c.v;
    }
    f32x4 acc1[4][4];
    #pragma unroll
    for (int ct = 0; ct < 4; ct++) {
        U4B8 w; w.u = wpack[(2 + ct) * 64 + L];
        float au = fbuf[64 + ct * 16 + m];
        #pragma unroll
        for (int rt = 0; rt < 4; rt++) {
            f32x4 a = { au, au, au, au };
            acc1[rt][ct] = __builtin_amdgcn_mfma_f32_16x16x32_bf16(A1[rt], w.v, a, 0, 0, 0);
        }
    }
    float g1c[4], be1c[4];
    #pragma unroll
    for (int ct = 0; ct < 4; ct++) { g1c[ct] = g1[ct * 16 + m]; be1c[ct] = be1[ct * 16 + m]; }
    float a1mx[4] = { 0.f, 0.f, 0.f, 0.f };
    #pragma unroll
    for (int rt = 0; rt < 4; rt++) {
        #pragma unroll
        for (int reg = 0; reg < 4; reg++) {
            float rs = 0.f, rq = 0.f;
            #pragma unroll
            for (int ct = 0; ct < 4; ct++) { float x = acc1[rt][ct][reg]; rs += x; rq += x * x; }
            #pragma unroll
            for (int s = 1; s < 16; s <<= 1) { rs += __shfl_xor(rs, s, 64); rq += __shfl_xor(rq, s, 64); }
            float mu = rs * (1.f / 64.f);
            float var = rq * (1.f / 64.f) - mu * mu;
            float ri = rsqrtf(var + LN_EPS);
            #pragma unroll
            for (int ct = 0; ct < 4; ct++) {
                float v = fmaxf(fmaf(g1c[ct] * ri, acc1[rt][ct][reg] - mu, be1c[ct]), 0.f);
                acc1[rt][ct][reg] = v;
                a1mx[ct] = fmaxf(a1mx[ct], v);
            }
        }
    }
    #pragma unroll
    for (int ct = 0; ct < 4; ct++) {
        float v = a1mx[ct];
        v = fmaxf(v, __shfl_xor(v, 16, 64));
        v = fmaxf(v, __shfl_xor(v, 32, 64));
        a1mx[ct] = v;
    }
    __syncthreads();
    if (q == 0) {
        #pragma unroll
        for (int ct = 0; ct < 4; ct++) fbuf[ct * 16 + m] = a1mx[ct];
    }
    __syncthreads();
    float au2a = b2[L], au2b = b2[64 + L];
    for (int j = 0; j < 64; j++) {
        float av = fbuf[j];
        au2a = fmaf(av, W2[(64 + j) * 128 + L],      au2a);
        au2b = fmaf(av, W2[(64 + j) * 128 + 64 + L], au2b);
    }
    #pragma unroll
    for (int rt = 0; rt < 4; rt++)
        #pragma unroll
        for (int reg = 0; reg < 4; reg++) {
            int row = rt * 16 + q * 4 + reg;
            #pragma unroll
            for (int ct = 0; ct < 4; ct++)
                hbuf[row * 72 + ct * 16 + m] = (unsigned short)f2bf_u(acc1[rt][ct][reg]);
        }
    __syncthreads();
    fbuf[64 + L] = au2a; fbuf[128 + L] = au2b;
    __syncthreads();

    // ---------------- layer 2 : 128(per-row 64) -> 128 ----------------
    bf16x8 A2[4][2];
    #pragma unroll
    for (int rt = 0; rt < 4; rt++)
        #pragma unroll
        for (int ks = 0; ks < 2; ks++) {
            U4B8 c; c.u = *(const uint4*)(hbuf + (rt * 16 + m) * 72 + ks * 32 + q * 8);
            A2[rt][ks] = c.v;
        }
    f32x4 acc2[8][4];
    #pragma unroll
    for (int ct = 0; ct < 8; ct++) {
        U4B8 wa, wb;
        wa.u = wpack[(6 + ct) * 64 + L];
        wb.u = wpack[(14 + ct) * 64 + L];
        float au = fbuf[64 + ct * 16 + m];
        #pragma unroll
        for (int rt = 0; rt < 4; rt++) {
            f32x4 a = { au, au, au, au };
            a = __builtin_amdgcn_mfma_f32_16x16x32_bf16(A2[rt][0], wa.v, a, 0, 0, 0);
            a = __builtin_amdgcn_mfma_f32_16x16x32_bf16(A2[rt][1], wb.v, a, 0, 0, 0);
            acc2[ct][rt] = a;
        }
    }
    float g2c[8], be2c[8];
    #pragma unroll
    for (int ct = 0; ct < 8; ct++) { g2c[ct] = g2[ct * 16 + m]; be2c[ct] = be2[ct * 16 + m]; }
    float m2[8] = { 0.f, 0.f, 0.f, 0.f, 0.f, 0.f, 0.f, 0.f };
    #pragma unroll
    for (int rt = 0; rt < 4; rt++) {
        #pragma unroll
        for (int reg = 0; reg < 4; reg++) {
            float rs = 0.f, rq = 0.f;
            #pragma unroll
            for (int ct = 0; ct < 8; ct++) { float x = acc2[ct][rt][reg]; rs += x; rq += x * x; }
            #pragma unroll
            for (int s = 1; s < 16; s <<= 1) { rs += __shfl_xor(rs, s, 64); rq += __shfl_xor(rq, s, 64); }
            float mu = rs * (1.f / 128.f);
            float var = rq * (1.f / 128.f) - mu * mu;
            float ri = rsqrtf(var + LN_EPS);
            #pragma unroll
            for (int ct = 0; ct < 8; ct++) {
                float v = fmaxf(fmaf(g2c[ct] * ri, acc2[ct][rt][reg] - mu, be2c[ct]), 0.f);
                m2[ct] = fmaxf(m2[ct], v);
            }
        }
    }
    #pragma unroll
    for (int ct = 0; ct < 8; ct++) {
        float v = m2[ct];
        v = fmaxf(v, __shfl_xor(v, 16, 64));
        v = fmaxf(v, __shfl_xor(v, 32, 64));
        m2[ct] = v;
    }
    // lane L stores cols L and 64+L:  col = (q or 4+q)*16 + m
    float v1 = q == 0 ? m2[0] : q == 1 ? m2[1] : q == 2 ? m2[2] : m2[3];
    float v2 = q == 0 ? m2[4] : q == 1 ? m2[5] : q == 2 ? m2[6] : m2[7];
    float* op = Ph + (size_t)blk * 128;
    op[L] = v1; op[64 + L] = v2;
}

// ---------------------------------------------------------------------------
// vn_attn: per-batch tail on folded matrices.
//   tt = pah @ Mff + u0f ; scores = Ph . tt / 16 ; softmax ;
//   out = (sum att*Ph) @ Wvf + bv
// ---------------------------------------------------------------------------
__global__ __launch_bounds__(256) void vn_attn(
    const float* __restrict__ data, const float* __restrict__ Ph,
    const float* __restrict__ Mff, const float* __restrict__ u0f,
    const float* __restrict__ Wvf, const float* __restrict__ bv,
    float* __restrict__ out)
{
    __shared__ float pah[128], tts[128], sc[256], pb[128], red[8];
    const int b = blockIdx.x, tid = threadIdx.x, lane = tid & 63, wave = tid >> 6;
    const float* PhB = Ph + (size_t)b * NPOLY * 128;
    const int agent = (int)data[(size_t)b * NV * LCH];

    if (tid < 128) pah[tid] = PhB[(size_t)agent * 128 + tid];
    __syncthreads();
    if (tid < 128) {
        float a = u0f[tid];
        for (int i = 0; i < 128; i++) a = fmaf(pah[i], Mff[i * 128 + tid], a);
        tts[tid] = a;
    }
    __syncthreads();
    for (int pi = 0; pi < 64; pi++) {
        const int p = wave * 64 + pi;
        const float* pr = PhB + (size_t)p * 128;
        float s = pr[lane] * tts[lane];
        s = fmaf(pr[64 + lane], tts[64 + lane], s);
        #pragma unroll
        for (int st = 1; st < 64; st <<= 1) s += __shfl_xor(s, st, 64);
        if (lane == 0) sc[p] = s * 0.0625f;
    }
    __syncthreads();
    float sv = sc[tid];
    float mx = sv;
    #pragma unroll
    for (int s = 1; s < 64; s <<= 1) mx = fmaxf(mx, __shfl_xor(mx, s, 64));
    if (lane == 0) red[wave] = mx;
    __syncthreads();
    mx = fmaxf(fmaxf(red[0], red[1]), fmaxf(red[2], red[3]));
    float e = expf(sv - mx);
    float sm = e;
    #pragma unroll
    for (int s = 1; s < 64; s <<= 1) sm += __shfl_xor(sm, s, 64);
    if (lane == 0) red[4 + wave] = sm;
    __syncthreads();
    const float tot = red[4] + red[5] + red[6] + red[7];
    sc[tid] = e / tot;
    __syncthreads();
    if (tid < 128) {
        float a = 0.f;
        for (int p = 0; p < 256; p++) a = fmaf(sc[p], PhB[(size_t)p * 128 + tid], a);
        pb[tid] = a;
    }
    __syncthreads();
    float o = bv[tid];
    for (int j = 0; j < 128; j++) o = fmaf(pb[j], Wvf[j * 256 + tid], o);
    out[(size_t)b * 256 + tid] = o;
}

extern "C" void kernel_launch(void* const* d_in, const int* in_sizes, int n_in,
                              void* d_out, int out_size, void* d_ws, size_t ws_size,
                              hipStream_t stream)
{
    const float* data = (const float*)d_in[0];
    const float* W0 = (const float*)d_in[1];
    const float* b0 = (const float*)d_in[2];
    const float* g0 = (const float*)d_in[3];
    const float* be0= (const float*)d_in[4];
    const float* W1 = (const float*)d_in[5];
    const float* b1 = (const float*)d_in[6];
    const float* g1 = (const float*)d_in[7];
    const float* be1= (const float*)d_in[8];
    const float* W2 = (const float*)d_in[9];
    const float* b2 = (const float*)d_in[10];
    const float* g2 = (const float*)d_in[11];
    const float* be2= (const float*)d_in[12];
    const float* Wq = (const float*)d_in[13];
    const float* bq = (const float*)d_in[14];
    const float* Wk = (const float*)d_in[15];
    const float* bk = (const float*)d_in[16];
    const float* Wv = (const float*)d_in[17];
    const float* bv = (const float*)d_in[18];
    (void)bk;

    char* wsb = (char*)d_ws;
    float* Ph    = (float*)(wsb);                  // 4 MB
    float* Wqf   = (float*)(wsb + 4194304);        // 128 KB
    float* Wkf   = (float*)(wsb + 4325376);        // 128 KB
    float* Wvf   = (float*)(wsb + 4456448);        // 128 KB
    float* Mff   = (float*)(wsb + 4587520);        // 64 KB
    float* u0f   = (float*)(wsb + 4653056);        // 512 B
    uint4* wpack = (uint4*)(wsb + 4653568);        // 22 KB

    vn_prep1<<<390, 256, 0, stream>>>(W0, W1, W2, Wq, Wk, Wv, Wqf, Wkf, Wvf, wpack);
    vn_prep2<<<65, 256, 0, stream>>>(Wqf, Wkf, bq, Mff, u0f);
    vn_mlp<<<32 * NPOLY, 64, 0, stream>>>(data, wpack,
                                          b0, g0, be0,
                                          W1, b1, g1, be1,
                                          W2, b2, g2, be2, Ph);
    vn_attn<<<32, 256, 0, stream>>>(data, Ph, Mff, u0f, Wvf, bv, (float*)d_out);
}